// Round 6
// baseline (616.918 us; speedup 1.0000x reference)
//
#include <hip/hip_runtime.h>
#include <stdint.h>
#include <math.h>

typedef unsigned short ushort_t;
typedef __attribute__((ext_vector_type(8))) short bf16x8;
typedef __attribute__((ext_vector_type(4))) float f32x4;

#define EPI_STRIDE 528   // 132 f32 per LDS row (conflict-free epilogue)

__device__ __forceinline__ ushort_t f2bf(float f) {
  union { float f; unsigned u; } cv; cv.f = f;
  unsigned r = cv.u + 0x7fffu + ((cv.u >> 16) & 1u);
  return (ushort_t)(r >> 16);
}

__device__ __forceinline__ void gl_lds16(const void* g, void* l) {
  typedef __attribute__((address_space(1))) const char gchar;
  typedef __attribute__((address_space(3))) char lchar;
  __builtin_amdgcn_global_load_lds((gchar*)g, (lchar*)l, 16, 0, 0);
}

__device__ __forceinline__ f32x4 MFMA(bf16x8 a, bf16x8 b, f32x4 c) {
  return __builtin_amdgcn_mfma_f32_16x16x32_bf16(a, b, c, 0, 0, 0);
}

// ---------------- LayerNorm (fp32 in) -> bf16 xn ----------------
__global__ __launch_bounds__(256) void ln_kernel(const float* __restrict__ x,
                                                 const float* __restrict__ gamma,
                                                 const float* __restrict__ beta,
                                                 ushort_t* __restrict__ xn) {
  const int row = blockIdx.x;
  const int t = threadIdx.x;
  const float4 v = ((const float4*)(x + (size_t)row * 1024))[t];
  float s  = v.x + v.y + v.z + v.w;
  float ss = v.x * v.x + v.y * v.y + v.z * v.z + v.w * v.w;
#pragma unroll
  for (int o = 32; o >= 1; o >>= 1) {
    s  += __shfl_xor(s, o);
    ss += __shfl_xor(ss, o);
  }
  __shared__ float red[10];
  const int wave = t >> 6, lane = t & 63;
  if (lane == 0) { red[wave] = s; red[4 + wave] = ss; }
  __syncthreads();
  if (t == 0) {
    float S  = red[0] + red[1] + red[2] + red[3];
    float SS = red[4] + red[5] + red[6] + red[7];
    float mu  = S * (1.0f / 1024.0f);
    float var = SS * (1.0f / 1024.0f) - mu * mu;
    red[8] = mu;
    red[9] = rsqrtf(var + 1e-5f);
  }
  __syncthreads();
  const float mu = red[8], rs = red[9];
  const float4 g = ((const float4*)gamma)[t];
  const float4 b = ((const float4*)beta)[t];
  ushort4 o;
  o.x = f2bf((v.x - mu) * rs * g.x + b.x);
  o.y = f2bf((v.y - mu) * rs * g.y + b.y);
  o.z = f2bf((v.z - mu) * rs * g.z + b.z);
  o.w = f2bf((v.w - mu) * rs * g.w + b.w);
  ((ushort4*)(xn + (size_t)row * 1024))[t] = o;
}

// ---------------- transpose + cast: in[e][R][C] fp32 -> out[e][C][R] bf16 ----------------
__global__ __launch_bounds__(256) void transpose_cast(const float* __restrict__ in,
                                                      ushort_t* __restrict__ out,
                                                      int R, int C) {
  __shared__ float tile[32][33];
  const int e = blockIdx.z;
  const float* src = in + (size_t)e * R * C;
  ushort_t* dst = out + (size_t)e * R * C;
  const int c0 = blockIdx.x * 32, r0 = blockIdx.y * 32;
  const int tx = threadIdx.x, ty = threadIdx.y;
#pragma unroll
  for (int j = 0; j < 32; j += 8)
    tile[ty + j][tx] = src[(size_t)(r0 + ty + j) * C + c0 + tx];
  __syncthreads();
#pragma unroll
  for (int j = 0; j < 32; j += 8)
    dst[(size_t)(c0 + ty + j) * R + r0 + tx] = f2bf(tile[tx][ty + j]);
}

// ======== 128x128 / BK=32 m97-style GEMM: single-buffer, 2-barrier loop, ========
// ======== multi-block-per-CU overlap; XOR-swizzled LDS; LDS-gather epilogue =====
// sA [128 rows][32 k] @0 (8KB), sB @8192. Rows = 64B (4 x 16B granules).
// Swizzle: global granule g of row r lives at LDS granule g ^ ((r>>1)&3).
// Epilogue reuses smem as [32][EPI_STRIDE] f32.

template <int EPI, int LDA, int LDC, int KTOT, int LOG_NTN>
__global__ __launch_bounds__(256) void gemm128(const ushort_t* __restrict__ A,
                                               const ushort_t* __restrict__ Bw,
                                               const float* __restrict__ bias,
                                               const float* __restrict__ resid,
                                               ushort_t* __restrict__ Hout,
                                               float* __restrict__ Fout) {
  __shared__ char smem[32 * EPI_STRIDE];   // 16896 B >= 16384 main-loop bytes
  const int tid = threadIdx.x;
  const int wave = tid >> 6, lane = tid & 63;

  // XCD-aware bijective swizzle: 8 XCDs x (16 m-tiles x NTN n-tiles) each
  const int bid = blockIdx.x;
  const int c = bid & 7, l = bid >> 3;
  const int tm = c * 16 + (l >> LOG_NTN);
  const int tn = l & ((1 << LOG_NTN) - 1);
  const int row0 = tm * 128;
  const int col0 = tn * 128;
  const int e = (tm >> 2) & 7;

  const ushort_t* gA = A + (size_t)row0 * LDA;
  const ushort_t* gB = Bw + ((size_t)e * LDC + col0) * LDA;

  // staging addresses: per thread 2 A-loads + 2 B-loads per tile
  const int srow = wave * 16 + (lane >> 2);                 // pass-0 row
  const int gs = ((lane & 3) ^ ((lane >> 3) & 3)) * 8;      // inverse-swizzled k elems
  char* const dA0 = smem + wave * 1024;                     // + lane*16 by HW
  char* const dA1 = smem + 4096 + wave * 1024;
  char* const dB0 = smem + 8192 + wave * 1024;
  char* const dB1 = smem + 12288 + wave * 1024;

  // fragment read offsets (swizzled)
  const int wr = wave >> 1, wc = wave & 1;
  const int l15 = lane & 15, g = lane >> 4;
  const int sw = ((g ^ ((l15 >> 1) & 3)) << 4);
  const int a_off = wr * 4096 + l15 * 64 + sw;
  const int b_off = 8192 + wc * 4096 + l15 * 64 + sw;

  f32x4 acc[4][4] = {};

  for (int kt = 0; kt < KTOT; kt += 32) {
    gl_lds16(gA + (size_t)srow * LDA + kt + gs,        dA0);
    gl_lds16(gA + (size_t)(srow + 64) * LDA + kt + gs, dA1);
    gl_lds16(gB + (size_t)srow * LDA + kt + gs,        dB0);
    gl_lds16(gB + (size_t)(srow + 64) * LDA + kt + gs, dB1);
    __syncthreads();                       // drains vmcnt(0): tile ready
    bf16x8 a[4], b[4];
#pragma unroll
    for (int ni = 0; ni < 4; ni++) b[ni] = *(const bf16x8*)(smem + b_off + ni * 1024);
#pragma unroll
    for (int mi = 0; mi < 4; mi++) a[mi] = *(const bf16x8*)(smem + a_off + mi * 1024);
#pragma unroll
    for (int mi = 0; mi < 4; mi++)
#pragma unroll
      for (int ni = 0; ni < 4; ni++)
        acc[mi][ni] = MFMA(a[mi], b[ni], acc[mi][ni]);
    __syncthreads();                       // reads done before next-tile stores
  }

  // ---------------- LDS-gather epilogue: 4 rounds x 32 rows ----------------
  float bv[4];
#pragma unroll
  for (int ni = 0; ni < 4; ni++)
    bv[ni] = bias[e * LDC + col0 + wc * 64 + ni * 16 + l15];

#pragma unroll
  for (int r = 0; r < 4; ++r) {
    // write side: waves with wr == r>>1 own rows [r*32, r*32+32)
    if (wr == (r >> 1)) {
#pragma unroll
      for (int mh = 0; mh < 2; ++mh) {
        const int lrow = mh * 16 + g * 4;
#pragma unroll
        for (int ni = 0; ni < 4; ++ni) {
          const int colb = (wc * 64 + ni * 16 + l15) * 4;
          const int mi = (r & 1) * 2 + mh;
#pragma unroll
          for (int rr = 0; rr < 4; ++rr) {
            float v = acc[mi][ni][rr] + bv[ni];
            if (EPI == 0) {
              float v2 = v * v;
              float cc = fmaf(0.044715f, v2, 1.0f);
              float u  = exp2f(-2.3022078f * v * cc);
              v = __fdividef(v, 1.0f + u);
            }
            *(float*)(smem + (size_t)(lrow + rr) * EPI_STRIDE + colb) = v;
          }
        }
      }
    }
    __syncthreads();
    // read side: 32 rows x 128 cols, coalesced wide stores
#pragma unroll
    for (int i = 0; i < 4; ++i) {
      const int chunk = i * 256 + tid;
      const int lr = chunk >> 5;
      const int c4 = chunk & 31;
      const float4 v4 = *(const float4*)(smem + (size_t)lr * EPI_STRIDE + c4 * 16);
      const int grow = row0 + r * 32 + lr;
      const int gcol = col0 + c4 * 4;
      if (EPI == 0) {
        ushort4 o;
        o.x = f2bf(v4.x); o.y = f2bf(v4.y); o.z = f2bf(v4.z); o.w = f2bf(v4.w);
        *(ushort4*)(&Hout[(size_t)grow * LDC + gcol]) = o;
      } else {
        const float4 rs = *(const float4*)(&resid[(size_t)grow * LDC + gcol]);
        float4 o;
        o.x = v4.x + rs.x; o.y = v4.y + rs.y; o.z = v4.z + rs.z; o.w = v4.w + rs.w;
        *(float4*)(&Fout[(size_t)grow * LDC + gcol]) = o;
      }
    }
    __syncthreads();
  }
}

extern "C" void kernel_launch(void* const* d_in, const int* in_sizes, int n_in,
                              void* d_out, int out_size, void* d_ws, size_t ws_size,
                              hipStream_t stream) {
  const float* x     = (const float*)d_in[0];
  const float* gamma = (const float*)d_in[1];
  const float* beta  = (const float*)d_in[2];
  // d_in[3] = gate_w : logits discarded by the reference -> skip
  const float* w1    = (const float*)d_in[4];
  const float* b1    = (const float*)d_in[5];
  const float* w2    = (const float*)d_in[6];
  const float* b2    = (const float*)d_in[7];
  float* out = (float*)d_out;

  char* ws = (char*)d_ws;
  ushort_t* xn  = (ushort_t*)ws;                                   // 32MB
  ushort_t* w1t = (ushort_t*)(ws + 33554432);                      // 64MB
  ushort_t* w2t = (ushort_t*)(ws + 33554432 + 67108864);           // 64MB
  ushort_t* h   = (ushort_t*)(ws + 33554432 + 2 * 67108864);       // 128MB

  ln_kernel<<<16384, 256, 0, stream>>>(x, gamma, beta, xn);
  transpose_cast<<<dim3(128, 32, 8), dim3(32, 8), 0, stream>>>(w1, w1t, 1024, 4096);
  transpose_cast<<<dim3(32, 128, 8), dim3(32, 8), 0, stream>>>(w2, w2t, 4096, 1024);

  // GEMM1: M=16384 N=4096 K=1024 -> h = gelu(xn@w1 + b1); grid 128 m x 32 n
  gemm128<0, 1024, 4096, 1024, 5><<<dim3(4096), 256, 0, stream>>>(xn, w1t, b1, nullptr, h, nullptr);
  // GEMM2: M=16384 N=1024 K=4096 -> out = x + h@w2 + b2; grid 128 m x 8 n
  gemm128<1, 4096, 1024, 4096, 3><<<dim3(1024), 256, 0, stream>>>(h, w2t, b2, x, nullptr, out);
}

// Round 7
// 424.952 us; speedup vs baseline: 1.4517x; 1.4517x over previous
//
#include <hip/hip_runtime.h>
#include <stdint.h>
#include <math.h>

typedef unsigned short ushort_t;
typedef __attribute__((ext_vector_type(8))) short bf16x8;
typedef __attribute__((ext_vector_type(4))) float f32x4;

#define SLOT 32768
#define EPI_STRIDE 1032   // 258 f32 per LDS row (conflict-free epilogue)

__device__ __forceinline__ ushort_t f2bf(float f) {
  union { float f; unsigned u; } cv; cv.f = f;
  unsigned r = cv.u + 0x7fffu + ((cv.u >> 16) & 1u);
  return (ushort_t)(r >> 16);
}

__device__ __forceinline__ void gl_lds16(const void* g, void* l) {
  typedef __attribute__((address_space(1))) const char gchar;
  typedef __attribute__((address_space(3))) char lchar;
  __builtin_amdgcn_global_load_lds((gchar*)g, (lchar*)l, 16, 0, 0);
}

__device__ __forceinline__ f32x4 MFMA(bf16x8 a, bf16x8 b, f32x4 c) {
  return __builtin_amdgcn_mfma_f32_16x16x32_bf16(a, b, c, 0, 0, 0);
}

// ---------------- LayerNorm (fp32 in) -> bf16 xn ----------------
__global__ __launch_bounds__(256) void ln_kernel(const float* __restrict__ x,
                                                 const float* __restrict__ gamma,
                                                 const float* __restrict__ beta,
                                                 ushort_t* __restrict__ xn) {
  const int row = blockIdx.x;
  const int t = threadIdx.x;
  const float4 v = ((const float4*)(x + (size_t)row * 1024))[t];
  float s  = v.x + v.y + v.z + v.w;
  float ss = v.x * v.x + v.y * v.y + v.z * v.z + v.w * v.w;
#pragma unroll
  for (int o = 32; o >= 1; o >>= 1) {
    s  += __shfl_xor(s, o);
    ss += __shfl_xor(ss, o);
  }
  __shared__ float red[10];
  const int wave = t >> 6, lane = t & 63;
  if (lane == 0) { red[wave] = s; red[4 + wave] = ss; }
  __syncthreads();
  if (t == 0) {
    float S  = red[0] + red[1] + red[2] + red[3];
    float SS = red[4] + red[5] + red[6] + red[7];
    float mu  = S * (1.0f / 1024.0f);
    float var = SS * (1.0f / 1024.0f) - mu * mu;
    red[8] = mu;
    red[9] = rsqrtf(var + 1e-5f);
  }
  __syncthreads();
  const float mu = red[8], rs = red[9];
  const float4 g = ((const float4*)gamma)[t];
  const float4 b = ((const float4*)beta)[t];
  ushort4 o;
  o.x = f2bf((v.x - mu) * rs * g.x + b.x);
  o.y = f2bf((v.y - mu) * rs * g.y + b.y);
  o.z = f2bf((v.z - mu) * rs * g.z + b.z);
  o.w = f2bf((v.w - mu) * rs * g.w + b.w);
  ((ushort4*)(xn + (size_t)row * 1024))[t] = o;
}

// ---------------- transpose + cast: in[e][R][C] fp32 -> out[e][C][R] bf16 ----------------
__global__ __launch_bounds__(256) void transpose_cast(const float* __restrict__ in,
                                                      ushort_t* __restrict__ out,
                                                      int R, int C) {
  __shared__ float tile[32][33];
  const int e = blockIdx.z;
  const float* src = in + (size_t)e * R * C;
  ushort_t* dst = out + (size_t)e * R * C;
  const int c0 = blockIdx.x * 32, r0 = blockIdx.y * 32;
  const int tx = threadIdx.x, ty = threadIdx.y;
#pragma unroll
  for (int j = 0; j < 32; j += 8)
    tile[ty + j][tx] = src[(size_t)(r0 + ty + j) * C + c0 + tx];
  __syncthreads();
#pragma unroll
  for (int j = 0; j < 32; j += 8)
    dst[(size_t)(c0 + ty + j) * R + r0 + tx] = f2bf(tile[tx][ty + j]);
}

// ======== 256x256 / BK=32 / ring-4, same-phase-read m201-style GEMM ========
// Slot (32KB): A-h0 @0, A-h1 @8192, B-h0 @16384, B-h1 @24576. Rows = 64B.
// Swizzle: global granule g of row r lives at LDS granule g ^ ((r>>1)&3).

__device__ __forceinline__ void stage_half(const ushort_t* gsrc, int lda,
                                           char* half_base, int kt, int tid) {
  const int rr = tid >> 2;
  const int gs = (tid & 3) ^ ((tid >> 3) & 3);
  gl_lds16(gsrc + (size_t)rr * lda + kt + gs * 8, half_base + (tid >> 6) * 1024);
}

template <int BASE>
__device__ __forceinline__ void mfma16(const bf16x8 (&a)[4], const bf16x8 (&b)[4],
                                       f32x4 (&acc)[8][4]) {
  __builtin_amdgcn_s_setprio(1);
#pragma unroll
  for (int mi = 0; mi < 4; mi++)
#pragma unroll
    for (int ni = 0; ni < 4; ni++)
      acc[BASE + mi][ni] = MFMA(a[mi], b[ni], acc[BASE + mi][ni]);
  __builtin_amdgcn_s_setprio(0);
}

// One K32 slot = 2 phases. Same-phase operand reads (m201 discipline):
// Phase A: {read B n0-3 + A m0-3; stage A(T+3); bar; lgkm0; 16 MFMA; bar}
// Phase B: {read A m4-7; stage B(T+3); bar; lgkm0; 16 MFMA; vmcnt(VM); bar}
template <int SIDX, int VM, bool STG>
__device__ __forceinline__ void slot_body(char* smem, int kt3,
                                          const ushort_t* gA, const ushort_t* gB,
                                          int lda, int a_off, int b_off, int tid,
                                          f32x4 (&acc)[8][4]) {
  const char* slot = smem + SIDX * SLOT;
  char* nstg = smem + ((SIDX + 3) & 3) * SLOT;
  bf16x8 a[4], b[4];
  // ---- phase A ----
#pragma unroll
  for (int ni = 0; ni < 4; ni++) b[ni] = *(const bf16x8*)(slot + b_off + ni * 1024);
#pragma unroll
  for (int mi = 0; mi < 4; mi++) a[mi] = *(const bf16x8*)(slot + a_off + mi * 1024);
  if (STG) {
    stage_half(gA, lda, nstg, kt3, tid);
    stage_half(gA + (size_t)128 * lda, lda, nstg + 8192, kt3, tid);
  }
  __builtin_amdgcn_sched_barrier(0);
  __builtin_amdgcn_s_barrier();
  asm volatile("s_waitcnt lgkmcnt(0)" ::: "memory");
  __builtin_amdgcn_sched_barrier(0);
  mfma16<0>(a, b, acc);
  __builtin_amdgcn_sched_barrier(0);
  __builtin_amdgcn_s_barrier();
  // ---- phase B ----
#pragma unroll
  for (int mi = 0; mi < 4; mi++) a[mi] = *(const bf16x8*)(slot + a_off + (mi + 4) * 1024);
  if (STG) {
    stage_half(gB, lda, nstg + 16384, kt3, tid);
    stage_half(gB + (size_t)128 * lda, lda, nstg + 24576, kt3, tid);
  }
  __builtin_amdgcn_sched_barrier(0);
  __builtin_amdgcn_s_barrier();
  asm volatile("s_waitcnt lgkmcnt(0)" ::: "memory");
  __builtin_amdgcn_sched_barrier(0);
  mfma16<4>(a, b, acc);
  __builtin_amdgcn_sched_barrier(0);
  // slot-boundary staging join: slot T+1's stages (oldest 4 of 12) must land
  if (VM == 8)      asm volatile("s_waitcnt vmcnt(8)" ::: "memory");
  else if (VM == 4) asm volatile("s_waitcnt vmcnt(4)" ::: "memory");
  else if (VM == 0) asm volatile("s_waitcnt vmcnt(0)" ::: "memory");
  __builtin_amdgcn_s_barrier();
}

// EPI=0: H = gelu(A@B + bias), bf16. EPI=1: O = resid + A@B + bias, f32.
template <int EPI, int LDA, int LDC, int KTOT>
__global__ __launch_bounds__(512, 2) void gemm256(const ushort_t* __restrict__ A,
                                                  const ushort_t* __restrict__ Bw,
                                                  const float* __restrict__ bias,
                                                  const float* __restrict__ resid,
                                                  ushort_t* __restrict__ Hout,
                                                  float* __restrict__ Fout) {
  extern __shared__ char smem[];
  const int tid = threadIdx.x;
  const int wave = tid >> 6, lane = tid & 63;

  const int bid = blockIdx.x;
  const int c = bid & 7, l = bid >> 3;
  const int tm = c * 8 + (l & 7);
  const int tn = l >> 3;
  const int row0 = tm * 256;
  const int col0 = tn * 256;
  const int e = (row0 >> 9) & 7;

  const ushort_t* gA = A + (size_t)row0 * LDA;
  const ushort_t* gB = Bw + ((size_t)e * LDC + col0) * LDA;

  const int NT = KTOT / 32;   // multiple of 4

  const int wm = wave >> 2, wn = wave & 3;
  const int l15 = lane & 15, g = lane >> 4;
  const int sw = ((g ^ ((lane >> 1) & 3)) << 4);
  const int a_off = wm * 8192 + l15 * 64 + sw;
  const int b_off = 16384 + (wn >> 1) * 8192 + (wn & 1) * 4096 + l15 * 64 + sw;

  f32x4 acc[8][4] = {};

  // prologue: stage slots 0,1,2 (12 instrs/wave); slot 0 = oldest 4 -> vmcnt(8)
#pragma unroll
  for (int T = 0; T < 3; ++T) {
    char* s = smem + T * SLOT;
    stage_half(gA, LDA, s, T * 32, tid);
    stage_half(gA + (size_t)128 * LDA, LDA, s + 8192, T * 32, tid);
    stage_half(gB, LDA, s + 16384, T * 32, tid);
    stage_half(gB + (size_t)128 * LDA, LDA, s + 24576, T * 32, tid);
  }
  asm volatile("s_waitcnt vmcnt(8)" ::: "memory");
  __builtin_amdgcn_s_barrier();

  for (int T = 0; T < NT - 4; T += 4) {
    slot_body<0, 8, true>(smem, (T + 3) * 32, gA, gB, LDA, a_off, b_off, tid, acc);
    slot_body<1, 8, true>(smem, (T + 4) * 32, gA, gB, LDA, a_off, b_off, tid, acc);
    slot_body<2, 8, true>(smem, (T + 5) * 32, gA, gB, LDA, a_off, b_off, tid, acc);
    slot_body<3, 8, true>(smem, (T + 6) * 32, gA, gB, LDA, a_off, b_off, tid, acc);
  }
  // tail slots NT-4..NT-1 (NT%4==0 -> SIDX 0..3); slot NT-4 still stages NT-1
  slot_body<0, 8, true >(smem, (NT - 1) * 32, gA, gB, LDA, a_off, b_off, tid, acc);
  slot_body<1, 4, false>(smem, 0,             gA, gB, LDA, a_off, b_off, tid, acc);
  slot_body<2, 0, false>(smem, 0,             gA, gB, LDA, a_off, b_off, tid, acc);
  slot_body<3, -1, false>(smem, 0,            gA, gB, LDA, a_off, b_off, tid, acc);

  // ---------------- LDS-gather epilogue: 4 rounds x 64 rows ----------------
  __syncthreads();   // drain all LDS reads before reuse

  float bv[4];
#pragma unroll
  for (int ni = 0; ni < 4; ni++)
    bv[ni] = bias[e * LDC + col0 + wn * 64 + ni * 16 + l15];

#pragma unroll
  for (int r = 0; r < 4; ++r) {
    // write side: frags mi = 2r, 2r+1 (rows wm*128 + [r*32, r*32+32))
#pragma unroll
    for (int mh = 0; mh < 2; ++mh) {
      const int mi = 2 * r + mh;
      const int lrow = wm * 32 + mh * 16 + g * 4;
#pragma unroll
      for (int ni = 0; ni < 4; ++ni) {
        const int colb = (wn * 64 + ni * 16 + l15) * 4;
#pragma unroll
        for (int rr = 0; rr < 4; ++rr) {
          float v = acc[mi][ni][rr] + bv[ni];
          if (EPI == 0) {
            float v2 = v * v;
            float cc = fmaf(0.044715f, v2, 1.0f);
            float u  = exp2f(-2.3022078f * v * cc);
            v = __fdividef(v, 1.0f + u);
          }
          *(float*)(smem + (size_t)(lrow + rr) * EPI_STRIDE + colb) = v;
        }
      }
    }
    __syncthreads();
    // read side: 64 rows x 256 cols, coalesced wide stores
#pragma unroll
    for (int i = 0; i < 8; ++i) {
      const int chunk = i * 512 + tid;
      const int lr = chunk >> 6;
      const int cb = (chunk & 63) * 16;
      const float4 v4 = *(const float4*)(smem + (size_t)lr * EPI_STRIDE + cb);
      const int grow = row0 + (lr < 32 ? r * 32 + lr : 128 + r * 32 + (lr - 32));
      const int gcol = col0 + (chunk & 63) * 4;
      if (EPI == 0) {
        ushort4 o;
        o.x = f2bf(v4.x); o.y = f2bf(v4.y); o.z = f2bf(v4.z); o.w = f2bf(v4.w);
        *(ushort4*)(&Hout[(size_t)grow * LDC + gcol]) = o;
      } else {
        const float4 rs = *(const float4*)(&resid[(size_t)grow * LDC + gcol]);
        float4 o;
        o.x = v4.x + rs.x; o.y = v4.y + rs.y; o.z = v4.z + rs.z; o.w = v4.w + rs.w;
        *(float4*)(&Fout[(size_t)grow * LDC + gcol]) = o;
      }
    }
    __syncthreads();
  }
}

extern "C" void kernel_launch(void* const* d_in, const int* in_sizes, int n_in,
                              void* d_out, int out_size, void* d_ws, size_t ws_size,
                              hipStream_t stream) {
  const float* x     = (const float*)d_in[0];
  const float* gamma = (const float*)d_in[1];
  const float* beta  = (const float*)d_in[2];
  // d_in[3] = gate_w : logits discarded by the reference -> skip
  const float* w1    = (const float*)d_in[4];
  const float* b1    = (const float*)d_in[5];
  const float* w2    = (const float*)d_in[6];
  const float* b2    = (const float*)d_in[7];
  float* out = (float*)d_out;

  char* ws = (char*)d_ws;
  ushort_t* xn  = (ushort_t*)ws;                                   // 32MB
  ushort_t* w1t = (ushort_t*)(ws + 33554432);                      // 64MB
  ushort_t* w2t = (ushort_t*)(ws + 33554432 + 67108864);           // 64MB
  ushort_t* h   = (ushort_t*)(ws + 33554432 + 2 * 67108864);       // 128MB

  hipFuncSetAttribute(reinterpret_cast<const void*>(&gemm256<0, 1024, 4096, 1024>),
                      hipFuncAttributeMaxDynamicSharedMemorySize, 131072);
  hipFuncSetAttribute(reinterpret_cast<const void*>(&gemm256<1, 4096, 1024, 4096>),
                      hipFuncAttributeMaxDynamicSharedMemorySize, 131072);

  ln_kernel<<<16384, 256, 0, stream>>>(x, gamma, beta, xn);
  transpose_cast<<<dim3(128, 32, 8), dim3(32, 8), 0, stream>>>(w1, w1t, 1024, 4096);
  transpose_cast<<<dim3(32, 128, 8), dim3(32, 8), 0, stream>>>(w2, w2t, 4096, 1024);

  // GEMM1: M=16384 N=4096 K=1024 -> h = gelu(xn@w1 + b1)
  gemm256<0, 1024, 4096, 1024><<<dim3(1024), 512, 131072, stream>>>(xn, w1t, b1, nullptr, h, nullptr);
  // GEMM2: M=16384 N=1024 K=4096 -> out = x + h@w2 + b2
  gemm256<1, 4096, 1024, 4096><<<dim3(256), 512, 131072, stream>>>(h, w2t, b2, x, nullptr, out);
}